// Round 3
// baseline (358.623 us; speedup 1.0000x reference)
//
#include <hip/hip_runtime.h>
#include <math.h>

// GAT 2-layer pipeline. CSR-by-dst built per launch via LDS-staged counting
// sort into FIXED-CAPACITY buckets (16384 slots/bucket; bucket load is
// Binomial(3.3M,1/391): mean 8448, sigma 92 -> cap is +86 sigma, unreachable).
// Aggregation: atomic-free per-node online softmax, bf16 features (absmax
// ~4e-3 << 1.1e-2 threshold). Layer-1 GEMM on MFMA (bf16): h^T = W^T . x^T.
// Sizes fixed by reference: F_IN=256, HEADS=8, HID=8 -> C1=64; layer2 1x1.
//
// R3: agg1 was at the scattered-L3 structural rate (224MB FETCH @3.1TB/s =
// 73us; h1 gather working set 12.8MB >> 4MB/XCD L2). Fix: IN-KERNEL src-slice
// phasing. k_bucket_csr now orders each dst list by (node, src/12500) -> 8
// slices of 1.6MB h1 each, and emits pcnt[n] = packed 8 x u8 per-slice counts.
// k_agg1 re-laned to 8 lanes/node x 8 feats/lane so per-lane phase state is
// 9 floats, staged in 18KB LDS across 2 node-groups; grid 1563 with
// launch_bounds(256,7) -> 7 blocks/CU, ALL blocks co-resident (single
// generation) -> waves walk slices in approximate lockstep -> per-phase
// gather working set ~2 slices (~3.2MB) fits L2. No __syncthreads (state is
// wave-private). Worst case (drift) degenerates to old miss behavior.
#define FIN 256
#define C1  64
#define NH  8
#define HID 8
#define MAXBUK 512        // buckets of 256 nodes; N=100000 -> 391 buckets
#define CAPLOG 14         // fixed bucket capacity 16384 edges
#define SC_CHUNK 8192     // edges per k_bscatter block (512 thr, EPT 16)
#define EPT (SC_CHUNK / 512)
#define NSLICE 8          // src slices for agg1 phasing
#define SLDIV 12500u      // slice = src / SLDIV (N=100000 -> 8 even slices)

typedef unsigned short ushort_t;
typedef unsigned int uint_t;
typedef __attribute__((ext_vector_type(8))) short short8;   // 8 x bf16 MFMA frag
typedef __attribute__((ext_vector_type(4))) float f32x4;    // MFMA acc

__device__ __forceinline__ ushort_t f2bf(float f) {   // round-to-nearest-even
    uint_t u = __float_as_uint(f);
    u += 0x7fffu + ((u >> 16) & 1u);
    return (ushort_t)(u >> 16);
}
__device__ __forceinline__ uint_t packbf2(float lo, float hi) {
    return (uint_t)f2bf(lo) | ((uint_t)f2bf(hi) << 16);
}
__device__ __forceinline__ float bf_lo(uint_t w) { return __uint_as_float(w << 16); }
__device__ __forceinline__ float bf_hi(uint_t w) { return __uint_as_float(w & 0xffff0000u); }

// ---------------- prep: zero bkt_cnt + transpose W -> global bf16 Wt[64][256] ----------------
__global__ void k_prep(const float* __restrict__ W, ushort_t* __restrict__ Wtg,
                       int* __restrict__ bkt_cnt) {
    int tid = blockIdx.x * 256 + threadIdx.x;
    if (tid < MAXBUK) bkt_cnt[tid] = 0;
    int c = tid >> 8;        // 0..63
    int k = tid & 255;       // 0..255
    Wtg[c * 256 + k] = f2bf(W[k * C1 + c]);
}

// ---------------- bucket scatter: packed edges into fixed-capacity buckets ----------------
__global__ __launch_bounds__(512) void k_bscatter(const int* __restrict__ ei, int E, int N,
                                                  int NBUK, int* __restrict__ bkt_cnt,
                                                  uint_t* __restrict__ ebuf) {
    __shared__ int hist[MAXBUK];
    __shared__ int loff[MAXBUK];     // local exclusive offsets; reused as rank cursor
    __shared__ int delta[MAXBUK];    // global_base - local_offset
    __shared__ int ssum[MAXBUK];
    __shared__ uint_t vals[SC_CHUNK];     // 32 KB
    __shared__ ushort_t buks[SC_CHUNK];   // 16 KB

    const int t = threadIdx.x;
    hist[t] = 0;
    __syncthreads();

    const int Etot = E + N;
    const int base0 = blockIdx.x * SC_CHUNK;
    const int lim = min(base0 + SC_CHUNK, Etot);
    const int cnt = lim - base0;

    uint_t myval[EPT];
    int myb[EPT];
#pragma unroll
    for (int i = 0; i < EPT; ++i) {
        int e = base0 + t + i * 512;
        if (e < lim) {
            int s, d;
            if (e < E) { s = ei[e]; d = ei[E + e]; } else { s = e - E; d = s; }
            myval[i] = ((uint_t)s << 8) | (uint_t)(d & 255);
            myb[i] = d >> 8;
            atomicAdd(&hist[myb[i]], 1);
        } else myb[i] = -1;
    }
    __syncthreads();

    // exclusive scan of hist[0..511] with 512 threads
    int v = hist[t];
    ssum[t] = v;
    __syncthreads();
    for (int o = 1; o < 512; o <<= 1) {
        int add = (t >= o) ? ssum[t - o] : 0;
        __syncthreads();
        ssum[t] += add;
        __syncthreads();
    }
    loff[t] = ssum[t] - v;   // exclusive
    __syncthreads();

    // global reservation: one atomic per touched bucket; base = b<<CAPLOG
    if (t < NBUK) {
        int c = hist[t];
        if (c) delta[t] = (t << CAPLOG) + atomicAdd(&bkt_cnt[t], c) - loff[t];
    }
    __syncthreads();

    // rank into staging (loff doubles as cursor; delta already captured)
#pragma unroll
    for (int i = 0; i < EPT; ++i) {
        if (myb[i] >= 0) {
            int pos = atomicAdd(&loff[myb[i]], 1);
            vals[pos] = myval[i];
            buks[pos] = (ushort_t)myb[i];
        }
    }
    __syncthreads();

    // linear write-out: consecutive i -> consecutive gaddr within each run
    for (int i = t; i < cnt; i += 512)
        ebuf[delta[buks[i]] + i] = vals[i];
}

// ---------------- per-bucket: degrees, offsets, per-slice counts, csr scatter ----------------
// One block (512 threads) per bucket. Histogram is (local_node, src_slice) =
// 2048 counters -> csr ordered by (node, slice); pcnt[n] = 8 x u8 slice
// counts (max per-slice deg ~ Binom(70,1/8) << 255). Scan: 4 counters/thread
// seq + 512-wide block scan.
__global__ __launch_bounds__(512) void k_bucket_csr(const uint_t* __restrict__ ebuf,
                                                    const int* __restrict__ bkt_cnt, int N,
                                                    int* __restrict__ deg, int* __restrict__ off,
                                                    int* __restrict__ csr,
                                                    uint2* __restrict__ pcnt) {
    __shared__ int hist[256 * NSLICE];   // 8 KB; counts, then cursors
    __shared__ int ssum[512];
    int b = blockIdx.x;
    int t = threadIdx.x;
    int beg = b << CAPLOG;
    int end = beg + bkt_cnt[b];
    for (int i = t; i < 256 * NSLICE; i += 512) hist[i] = 0;
    __syncthreads();
    for (int j = beg + t; j < end; j += 512) {
        uint_t v = ebuf[j];
        int key = ((v & 255u) << 3) | ((v >> 8) / SLDIV);
        atomicAdd(&hist[key], 1);
    }
    __syncthreads();
    // pcnt + deg (pure reads of hist)
    if (t < 256) {
        int node = (b << 8) + t;
        int c[8]; int s = 0;
#pragma unroll
        for (int i = 0; i < 8; ++i) { c[i] = hist[(t << 3) | i]; s += c[i]; }
        if (node < N) {
            deg[node] = s;
            uint2 pc;
            pc.x = (uint_t)c[0] | ((uint_t)c[1] << 8) | ((uint_t)c[2] << 16) | ((uint_t)c[3] << 24);
            pc.y = (uint_t)c[4] | ((uint_t)c[5] << 8) | ((uint_t)c[6] << 16) | ((uint_t)c[7] << 24);
            pcnt[node] = pc;
        }
    }
    // scan of 2048: thread t owns hist[4t..4t+3]
    int c0 = hist[4 * t], c1 = hist[4 * t + 1], c2 = hist[4 * t + 2], c3 = hist[4 * t + 3];
    int s4 = c0 + c1 + c2 + c3;
    __syncthreads();              // all reads of counts complete before overwrite
    ssum[t] = s4;
    __syncthreads();
    for (int o = 1; o < 512; o <<= 1) {
        int add = (t >= o) ? ssum[t - o] : 0;
        __syncthreads();
        ssum[t] += add;
        __syncthreads();
    }
    int base = beg + ssum[t] - s4;   // global exclusive prefix (cursor init)
    hist[4 * t]     = base;
    hist[4 * t + 1] = base + c0;
    hist[4 * t + 2] = base + c0 + c1;
    hist[4 * t + 3] = base + c0 + c1 + c2;
    __syncthreads();
    if (t < 256) {
        int node = (b << 8) + t;
        if (node < N) off[node] = hist[t << 3];
    }
    __syncthreads();
    for (int j = beg + t; j < end; j += 512) {
        uint_t v = ebuf[j];
        int key = ((v & 255u) << 3) | ((v >> 8) / SLDIV);
        int pos = atomicAdd(&hist[key], 1);
        csr[pos] = (int)(v >> 8);
    }
}

// ---------------- layer1 GEMM via MFMA + attention terms (bf16 outputs) ----------------
// h^T = W^T . x^T per mfma_f32_16x16x32_bf16 tile so D cols = nodes.
// NO LDS: A-fragments read from global bf16 Wt[64][256] (32KB, L1/L2
// resident). 64 nodes/block -> grid 1563, no staging prologue.
__global__ __launch_bounds__(256) void k_gemm1(
    const float* __restrict__ x, const ushort_t* __restrict__ Wtg,
    const float* __restrict__ att_s, const float* __restrict__ att_d,
    ushort_t* __restrict__ h1b, ushort_t* __restrict__ as1b, float* __restrict__ ad1, int N)
{
    const int t = threadIdx.x;
    const int wv = t >> 6, l = t & 63;
    const int l15 = l & 15, q = l >> 4;
    const int node = blockIdx.x * 64 + wv * 16 + l15;
    const bool ok = node < N;
    const float* xr = x + (size_t)(ok ? node : N - 1) * FIN;

    f32x4 acc[4];   // [ct] : output channels ct*16 + q*4 + 0..3, col = node
#pragma unroll
    for (int ct = 0; ct < 4; ++ct) acc[ct] = (f32x4){0.f, 0.f, 0.f, 0.f};

    for (int kk = 0; kk < 8; ++kk) {
        const int kof = kk * 32 + q * 8;
        short8 af[4];
#pragma unroll
        for (int ct = 0; ct < 4; ++ct)
            af[ct] = *reinterpret_cast<const short8*>(&Wtg[(ct * 16 + l15) * 256 + kof]);
        const float4* xp = reinterpret_cast<const float4*>(xr + kof);
        float4 v0 = xp[0], v1 = xp[1];
        union { short8 s; uint_t u[4]; } bu;
        bu.u[0] = packbf2(v0.x, v0.y);
        bu.u[1] = packbf2(v0.z, v0.w);
        bu.u[2] = packbf2(v1.x, v1.y);
        bu.u[3] = packbf2(v1.z, v1.w);
#pragma unroll
        for (int ct = 0; ct < 4; ++ct)
            acc[ct] = __builtin_amdgcn_mfma_f32_16x16x32_bf16(af[ct], bu.s, acc[ct], 0, 0, 0);
    }

    float4 ats[4], atd4[4];
#pragma unroll
    for (int ct = 0; ct < 4; ++ct) {
        ats[ct]  = *reinterpret_cast<const float4*>(&att_s[ct * 16 + q * 4]);
        atd4[ct] = *reinterpret_cast<const float4*>(&att_d[ct * 16 + q * 4]);
    }
    const int hb = q >> 1;

    float asp[8], adp[8];
#pragma unroll
    for (int h = 0; h < 8; ++h) { asp[h] = 0.f; adp[h] = 0.f; }
#pragma unroll
    for (int ct = 0; ct < 4; ++ct) {
        f32x4 a = acc[ct];
        if (ok) {
            uint2 hv;
            hv.x = packbf2(a[0], a[1]);
            hv.y = packbf2(a[2], a[3]);
            *reinterpret_cast<uint2*>(&h1b[(size_t)node * C1 + ct * 16 + q * 4]) = hv;
        }
        int h = ct * 2 + hb;
        asp[h] = a[0] * ats[ct].x + a[1] * ats[ct].y + a[2] * ats[ct].z + a[3] * ats[ct].w;
        adp[h] = a[0] * atd4[ct].x + a[1] * atd4[ct].y + a[2] * atd4[ct].z + a[3] * atd4[ct].w;
    }
#pragma unroll
    for (int o = 16; o <= 32; o <<= 1) {
#pragma unroll
        for (int h = 0; h < 8; ++h) {
            asp[h] += __shfl_xor(asp[h], o, 64);
            adp[h] += __shfl_xor(adp[h], o, 64);
        }
    }
    if (q == 0 && ok) {
        uint4 aw;
        aw.x = packbf2(asp[0], asp[1]);
        aw.y = packbf2(asp[2], asp[3]);
        aw.z = packbf2(asp[4], asp[5]);
        aw.w = packbf2(asp[6], asp[7]);
        *reinterpret_cast<uint4*>(&as1b[(size_t)node * NH]) = aw;
        *reinterpret_cast<float4*>(&ad1[(size_t)node * NH]) =
            make_float4(adp[0], adp[1], adp[2], adp[3]);
        *reinterpret_cast<float4*>(&ad1[(size_t)node * NH + 4]) =
            make_float4(adp[4], adp[5], adp[6], adp[7]);
    }
}

// ---------------- fused layer1 aggregation + bias/ELU + W2 projection ----------------
// Phased over 8 src-slices. 8 lanes/node x 8 feats/lane; 2 node-groups of 32
// per block; per-lane phase state (8 acc + den) staged in LDS (18KB). Grid
// 1563 @ 7 blocks/CU -> single block generation -> slices walked in rough
// lockstep -> gather working set ~2 slices (~3.2MB) fits per-XCD L2.
// State is wave-private -> NO __syncthreads.
__global__ __launch_bounds__(256, 7) void k_agg1(
    const int* __restrict__ csr, const int* __restrict__ off, const uint2* __restrict__ pcnt,
    const ushort_t* __restrict__ as1b, const float* __restrict__ ad1,
    const ushort_t* __restrict__ h1b,
    const float* __restrict__ b1, const float* __restrict__ W2,
    float* __restrict__ h2, int N)
{
    __shared__ float st[2][256][9];   // 18 KB: [group][lane][acc0..7, den]
    __shared__ int curp[2][32];       // per-(group,row) edge cursor (lane f==0 owns)
    const int t = threadIdx.x;
    const int row = t >> 3, f = t & 7;
    const int n0 = blockIdx.x * 64;

#pragma unroll
    for (int g = 0; g < 2; ++g) {
#pragma unroll
        for (int k = 0; k < 9; ++k) st[g][t][k] = 0.f;
        if (f == 0) {
            int n = n0 + g * 32 + row;
            curp[g][row] = (n < N) ? off[n] : 0;
        }
    }
    // no barrier: st[g][t] is thread-private; curp[g][row] shared only within
    // one 8-lane group of a single wave (program order + lgkmcnt suffice).

    for (int p = 0; p < NSLICE; ++p) {
#pragma unroll
        for (int g = 0; g < 2; ++g) {
            const int n = n0 + g * 32 + row;
            const bool ok = n < N;
            int cnt = 0, cur = 0;
            float adv = 0.f;
            if (ok) {
                uint2 pc = pcnt[n];
                uint_t w = (p < 4) ? pc.x : pc.y;
                cnt = (w >> ((p & 3) * 8)) & 255u;
                cur = curp[g][row];
                adv = ad1[(size_t)n * NH + f];
            }
            float a0 = st[g][t][0], a1 = st[g][t][1], a2 = st[g][t][2], a3 = st[g][t][3];
            float a4 = st[g][t][4], a5 = st[g][t][5], a6 = st[g][t][6], a7 = st[g][t][7];
            float den = st[g][t][8];
            for (int i = 0; i < cnt; ++i) {
                int s = csr[cur + i];
                float asv = __uint_as_float((uint_t)as1b[(size_t)s * NH + f] << 16);
                float tt = asv + adv;
                tt = fmaxf(tt, 0.2f * tt);
                float ex = __expf(tt);
                den += ex;
                uint4 hv = *reinterpret_cast<const uint4*>(&h1b[(size_t)s * C1 + f * 8]);
                a0 = fmaf(ex, bf_lo(hv.x), a0);
                a1 = fmaf(ex, bf_hi(hv.x), a1);
                a2 = fmaf(ex, bf_lo(hv.y), a2);
                a3 = fmaf(ex, bf_hi(hv.y), a3);
                a4 = fmaf(ex, bf_lo(hv.z), a4);
                a5 = fmaf(ex, bf_hi(hv.z), a5);
                a6 = fmaf(ex, bf_lo(hv.w), a6);
                a7 = fmaf(ex, bf_hi(hv.w), a7);
            }
            st[g][t][0] = a0; st[g][t][1] = a1; st[g][t][2] = a2; st[g][t][3] = a3;
            st[g][t][4] = a4; st[g][t][5] = a5; st[g][t][6] = a6; st[g][t][7] = a7;
            st[g][t][8] = den;
            if (f == 0 && ok) curp[g][row] = cur + cnt;
        }
    }

#pragma unroll
    for (int g = 0; g < 2; ++g) {
        const int n = n0 + g * 32 + row;
        if (n >= N) continue;   // uniform across each 8-lane group -> shfl safe
        float den = st[g][t][8];
        float inv = 1.f / (den + 1e-16f);
        float4 ba = *reinterpret_cast<const float4*>(&b1[f * 8]);
        float4 bb = *reinterpret_cast<const float4*>(&b1[f * 8 + 4]);
        float4 wa = *reinterpret_cast<const float4*>(&W2[f * 8]);
        float4 wb = *reinterpret_cast<const float4*>(&W2[f * 8 + 4]);
        float bv[8] = {ba.x, ba.y, ba.z, ba.w, bb.x, bb.y, bb.z, bb.w};
        float wv[8] = {wa.x, wa.y, wa.z, wa.w, wb.x, wb.y, wb.z, wb.w};
        float ps = 0.f;
#pragma unroll
        for (int k = 0; k < 8; ++k) {
            float v = st[g][t][k] * inv + bv[k];
            v = v > 0.f ? v : (__expf(v) - 1.f);  // ELU, fast path
            ps = fmaf(v, wv[k], ps);
        }
        ps += __shfl_xor(ps, 1, 64);
        ps += __shfl_xor(ps, 2, 64);
        ps += __shfl_xor(ps, 4, 64);
        if (f == 0) h2[n] = ps;
    }
}

// ---------------- fused layer2: softmax + aggregate + bias + sigmoid ----------------
__global__ __launch_bounds__(256) void k_agg2(
    const int* __restrict__ csr, const int* __restrict__ off, const int* __restrict__ deg,
    const float* __restrict__ h2,
    const float* __restrict__ ats2, const float* __restrict__ atd2,
    const float* __restrict__ b2, float* __restrict__ out, int N)
{
    int idx = blockIdx.x * 256 + threadIdx.x;
    int n = idx >> 4;
    int l16 = threadIdx.x & 15;
    if (n >= N) return;
    int beg = off[n];
    int end = beg + deg[n];
    float a_s = ats2[0], a_d = atd2[0];
    float adv = h2[n] * a_d;
    float den = 0.f, num = 0.f;
    for (int j = beg + l16; j < end; j += 16) {
        float hs = h2[csr[j]];
        float t = fmaf(hs, a_s, adv);
        t = fmaxf(t, 0.2f * t);
        float ex = __expf(t);
        den += ex;
        num = fmaf(ex, hs, num);
    }
#pragma unroll
    for (int o = 1; o <= 8; o <<= 1) {
        den += __shfl_xor(den, o, 64);
        num += __shfl_xor(num, o, 64);
    }
    if (l16 == 0) {
        float t = num / (den + 1e-16f) + b2[0];
        out[n] = 1.f / (1.f + __expf(-t));
    }
}

extern "C" void kernel_launch(void* const* d_in, const int* in_sizes, int n_in,
                              void* d_out, int out_size, void* d_ws, size_t ws_size,
                              hipStream_t stream)
{
    const float* x    = (const float*)d_in[0];
    const int*   ei   = (const int*)d_in[1];
    const float* W1   = (const float*)d_in[2];
    const float* ats1 = (const float*)d_in[3];
    const float* atd1 = (const float*)d_in[4];
    const float* b1   = (const float*)d_in[5];
    const float* W2   = (const float*)d_in[6];
    const float* ats2 = (const float*)d_in[7];
    const float* atd2 = (const float*)d_in[8];
    const float* b2   = (const float*)d_in[9];
    float* out = (float*)d_out;

    const int N = out_size;            // 100000
    const int E = in_sizes[1] / 2;     // 3200000
    const int Etot = E + N;
    const int NBUK = (N + 255) >> 8;   // 391 (<= MAXBUK)
    const size_t capElems = (size_t)NBUK << CAPLOG;   // 6.4M slots (25.6 MB)

    // workspace layout:
    //   union region: ebuf uint[NBUK<<CAPLOG] (25.6MB)  OVERLAYS  feature block
    //                 {h1b bf16[N*64], as1b bf16[N*8], ad1 f32[N*8], h2 f32[N]} (18MB)
    //   then ints: deg[N] off[N] bkt_cnt[512] csr[capElems] pcnt uint2[N] Wt bf16[64*256]
    char* base = (char*)d_ws;
    uint_t* ebuf = (uint_t*)base;
    ushort_t* h1b  = (ushort_t*)base;
    ushort_t* as1b = h1b + (size_t)N * C1;
    float* ad1 = (float*)(as1b + (size_t)N * NH);
    float* h2  = ad1 + (size_t)N * NH;
    size_t featBytes = (size_t)N * (C1 * 2 + NH * 2 + NH * 4 + 4);
    size_t unionBytes = capElems * sizeof(uint_t);
    if (featBytes > unionBytes) unionBytes = featBytes;
    unionBytes = (unionBytes + 255) & ~(size_t)255;
    int* deg     = (int*)(base + unionBytes);
    int* off     = deg + N;
    int* bkt_cnt = off + N;
    int* csr     = bkt_cnt + MAXBUK;
    uint2* pcnt  = (uint2*)(csr + capElems);         // 800 KB
    ushort_t* wtg = (ushort_t*)(pcnt + N);           // 32 KB global Wt

    k_prep<<<64, 256, 0, stream>>>(W1, wtg, bkt_cnt);
    k_bscatter<<<(Etot + SC_CHUNK - 1) / SC_CHUNK, 512, 0, stream>>>(ei, E, N, NBUK, bkt_cnt, ebuf);
    k_bucket_csr<<<NBUK, 512, 0, stream>>>(ebuf, bkt_cnt, N, deg, off, csr, pcnt);

    k_gemm1<<<(N + 63) / 64, 256, 0, stream>>>(x, wtg, ats1, atd1, h1b, as1b, ad1, N);
    k_agg1<<<(N + 63) / 64, 256, 0, stream>>>(csr, off, pcnt, as1b, ad1, h1b, b1, W2, h2, N);
    k_agg2<<<(N * 16 + 255) / 256, 256, 0, stream>>>(csr, off, deg, h2, ats2, atd2, b2, out, N);
}